// Round 14
// baseline (304.482 us; speedup 1.0000x reference)
//
#include <hip/hip_runtime.h>
#include <math.h>

typedef unsigned short u16;
typedef unsigned int   u32;

using f32x4  = __attribute__((ext_vector_type(4))) float;
using s16x8  = __attribute__((ext_vector_type(8))) short;
using u16x8  = __attribute__((ext_vector_type(8))) unsigned short;

// ---------- helpers ----------
__device__ __forceinline__ u16 f2b(float f) {           // fp32 -> bf16 RNE
    u32 u = __float_as_uint(f);
    u += 0x7FFFu + ((u >> 16) & 1u);
    return (u16)(u >> 16);
}
__device__ __forceinline__ float b2f(u16 u) { return __uint_as_float(((u32)u) << 16); }

// window-order row R -> natural token row (b*256 + i*16 + j)
__device__ __forceinline__ int natrow(int R) {
    int b = R >> 8, r8 = R & 255, w = r8 >> 2, t = r8 & 3;
    return (b << 8) + ((((w >> 3) << 1) + (t >> 1)) << 4) + ((w & 7) << 1) + (t & 1);
}

__device__ __forceinline__ void gll16(const void* g, void* l) {
    __builtin_amdgcn_global_load_lds(
        (const __attribute__((address_space(1))) void*)g,
        (__attribute__((address_space(3))) void*)l, 16, 0, 0);
}

// ---------- merged prologue ----------
// bid [0,3072): transpose_qkv (head-interleaved out)
// bid [3072,6144): transpose_pw (Wp, W1*g-folded, W2 -> contiguous)
// bid [6144,22528): ln1 row R = bid-6144 (natrow gather, f32 -> bf16)
// bid [22528,22592): cvec/dvec role: cvec[n]=sum_k g_k W1[k,n];
//                    dvp[n]=sum_k b_k W1[k,n] (+ b1[n] from block kb==0)
__global__ __launch_bounds__(256) void prologue_kernel(
    const float* __restrict__ x, const float* __restrict__ ln1g, const float* __restrict__ ln1b,
    const float* __restrict__ Wq, const float* __restrict__ Wk, const float* __restrict__ Wv,
    const float* __restrict__ Wp, const float* __restrict__ W1, const float* __restrict__ W2,
    const float* __restrict__ ln2g, const float* __restrict__ ln2b, const float* __restrict__ b1,
    u16* __restrict__ WqkvT, u16* __restrict__ WpT, u16* __restrict__ xw_b,
    float* __restrict__ cvec, float* __restrict__ dvp)
{
    const int bid = blockIdx.x;
    const int tid = threadIdx.x;
    if (bid < 6144) {
        // ---- transpose role: [R][C] f32 -> [C][R] bf16 (W1: fold ln2g by row) ----
        __shared__ float tile[32][33];
        const float* in; u16* out; int Cc, bx, by, gfold = 0;
        if (bid < 3072) {
            const int z = bid >> 6, r = bid & 63;
            bx = r & 1; by = r >> 1;
            in  = (z < 16 ? Wq : z < 32 ? Wk : Wv) + (size_t)(z & 15) * 65536;
            const int h = z & 15, sec = z < 16 ? 0 : (z < 32 ? 1 : 2);
            out = WqkvT + ((size_t)h * 192 + sec * 64) * 1024;
            Cc = 64;
        } else {
            const int t = bid - 3072, z = t >> 10, r = t & 1023;
            bx = r & 31; by = r >> 5;
            in  = z == 0 ? Wp : z == 1 ? W1 : W2;
            out = WpT + (size_t)z * 1048576;
            Cc = 1024; gfold = (z == 1);
        }
        const int tx = tid & 31, ty = tid >> 5;
        const int c  = bx * 32 + tx;
        const int r0 = by * 32;
#pragma unroll
        for (int i = 0; i < 32; i += 8) {
            const float gs = gfold ? ln2g[r0 + ty + i] : 1.f;
            tile[ty + i][tx] = in[(size_t)(r0 + ty + i) * Cc + c] * gs;
        }
        __syncthreads();
        const int orow0 = bx * 32;
        const int ocol  = r0 + tx;
#pragma unroll
        for (int i = 0; i < 32; i += 8)
            out[(size_t)(orow0 + ty + i) * 1024 + ocol] = f2b(tile[tx][ty + i]);
    } else if (bid < 22528) {
        // ---- LN1 role ----
        __shared__ float red[8];
        const int R   = bid - 6144;
        const int src = natrow(R);
        const float4 v = ((const float4*)(x + (size_t)src * 1024))[tid];
        float s  = v.x + v.y + v.z + v.w;
        float s2 = v.x * v.x + v.y * v.y + v.z * v.z + v.w * v.w;
#pragma unroll
        for (int o = 32; o; o >>= 1) { s += __shfl_xor(s, o); s2 += __shfl_xor(s2, o); }
        const int w = tid >> 6, l = tid & 63;
        if (l == 0) { red[w] = s; red[w + 4] = s2; }
        __syncthreads();
        s  = red[0] + red[1] + red[2] + red[3];
        s2 = red[4] + red[5] + red[6] + red[7];
        const float mean = s * (1.f / 1024.f);
        const float var  = s2 * (1.f / 1024.f) - mean * mean;
        const float rinv = rsqrtf(var + 1e-5f);
        const float4 gv = ((const float4*)ln1g)[tid];
        const float4 bv = ((const float4*)ln1b)[tid];
        ((ushort4*)(xw_b + (size_t)R * 1024))[tid] = make_ushort4(
            f2b((v.x - mean) * rinv * gv.x + bv.x), f2b((v.y - mean) * rinv * gv.y + bv.y),
            f2b((v.z - mean) * rinv * gv.z + bv.z), f2b((v.w - mean) * rinv * gv.w + bv.w));
    } else {
        // ---- cvec / dvec role: 64 blocks x 16 k-rows ----
        const int kb = bid - 22528;
        const int n0 = tid * 4;
        float pc[4] = {0, 0, 0, 0}, pd[4] = {0, 0, 0, 0};
        for (int r = 0; r < 16; ++r) {
            const int k = kb * 16 + r;
            const float gk = ln2g[k], bk = ln2b[k];
            const float4 wv = *(const float4*)&W1[(size_t)k * 1024 + n0];
            pc[0] += gk * wv.x; pc[1] += gk * wv.y; pc[2] += gk * wv.z; pc[3] += gk * wv.w;
            pd[0] += bk * wv.x; pd[1] += bk * wv.y; pd[2] += bk * wv.z; pd[3] += bk * wv.w;
        }
        if (kb == 0) {
            const float4 bb = *(const float4*)&b1[n0];
            pd[0] += bb.x; pd[1] += bb.y; pd[2] += bb.z; pd[3] += bb.w;
        }
#pragma unroll
        for (int c = 0; c < 4; ++c) {
            atomicAdd(&cvec[n0 + c], pc[c]);
            atomicAdd(&dvp[n0 + c], pd[c]);
        }
    }
}

// ---------- FUSED QKV GEMM + windowed attention (r12, unchanged) ----------
__global__ __launch_bounds__(512, 2) void gemm_qkv_attn(
    const u16* __restrict__ A, const u16* __restrict__ Bt,
    u16* __restrict__ Att, int M, int K)
{
    extern __shared__ char lds[];
    const int NT = K >> 6;                        // 16
    const int x = blockIdx.x & 7, i = blockIdx.x >> 3;
    const int sc = i >> 4, u = i & 15;
    const int scr = sc >> 2, scc = sc & 3;
    const int mb = x * 8 + scr * 4 + (u >> 2);
    const int nb = scc * 4 + (u & 3);             // head index 0..15
    const int row0 = mb * 256, col0 = nb * 192;
    const int tid = threadIdx.x;
    const int w = tid >> 6, l = tid & 63;
    const int wr = w & 3, wcg = w >> 2;
    const int lr = l & 15, kg = l >> 4;
    const int xs = (lr & 7) << 4;
    const int koff[2] = { (kg * 16) ^ xs, (64 + kg * 16) ^ xs };
    const int abase_l = wr * 8192 + lr * 128;
    const int bbase_l = wcg * 12288 + lr * 128;

    f32x4 acc[4][6] = {};
    s16x8 a[4][2], b[6][2];

    auto stageQ = [&](int ts) {
        if (ts >= NT) return;
        const int d = ts & 1, gcolb = ts * 64;
        const int sl = (tid & 7) ^ ((tid >> 3) & 7);
#pragma unroll
        for (int h2 = 0; h2 < 2; ++h2)
#pragma unroll
            for (int j = 0; j < 2; ++j) {
                const int c = j * 512 + tid;
                const int s2 = (c & 7) ^ ((c >> 3) & 7);
                gll16(A + (size_t)(row0 + h2 * 128 + (c >> 3)) * K + gcolb + s2 * 8,
                      lds + d * 32768 + h2 * 16384 + (j * 8 + w) * 1024);
            }
#pragma unroll
        for (int k2 = 0; k2 < 3; ++k2)
            gll16(Bt + (size_t)(col0 + k2 * 64 + (tid >> 3)) * K + gcolb + sl * 8,
                  lds + 65536 + d * 24576 + k2 * 8192 + w * 1024);
    };

#define SB __builtin_amdgcn_sched_barrier(0)
#define WLq(NS) do { asm volatile("s_waitcnt lgkmcnt(" NS ")" ::: "memory"); SB; } while (0)

    stageQ(0);

    for (int t = 0; t < NT; ++t) {
        const char* Ab = lds + (t & 1) * 32768 + abase_l;
        const char* Bb = lds + 65536 + (t & 1) * 24576 + bbase_l;
        asm volatile("s_waitcnt vmcnt(0)" ::: "memory");
        __builtin_amdgcn_s_barrier(); SB;
#pragma unroll
        for (int i2 = 0; i2 < 4; ++i2) a[i2][0] = *(const s16x8*)(Ab + i2 * 2048 + koff[0]);
#pragma unroll
        for (int n = 0; n < 6; ++n)   b[n][0]  = *(const s16x8*)(Bb + n * 2048 + koff[0]);
        SB;
#pragma unroll
        for (int i2 = 0; i2 < 4; ++i2) a[i2][1] = *(const s16x8*)(Ab + i2 * 2048 + koff[1]);
#pragma unroll
        for (int n = 0; n < 6; ++n)   b[n][1]  = *(const s16x8*)(Bb + n * 2048 + koff[1]);
        SB;
        stageQ(t + 1); SB;
        __builtin_amdgcn_s_setprio(1);
        WLq("10");
#pragma unroll
        for (int i2 = 0; i2 < 4; ++i2)
#pragma unroll
            for (int n = 0; n < 6; ++n)
                acc[i2][n] = __builtin_amdgcn_mfma_f32_16x16x32_bf16(a[i2][0], b[n][0], acc[i2][n], 0, 0, 0);
        SB;
        WLq("0");
#pragma unroll
        for (int i2 = 0; i2 < 4; ++i2)
#pragma unroll
            for (int n = 0; n < 6; ++n)
                acc[i2][n] = __builtin_amdgcn_mfma_f32_16x16x32_bf16(a[i2][1], b[n][1], acc[i2][n], 0, 0, 0);
        __builtin_amdgcn_s_setprio(0); SB;
    }
#undef WLq

    // epilogue: acc -> LDS (bf16, pitch 200) -> windowed attention -> Att
    __builtin_amdgcn_s_barrier();
    u16* attL = (u16*)lds;
#pragma unroll
    for (int i2 = 0; i2 < 4; ++i2)
#pragma unroll
        for (int n = 0; n < 6; ++n)
#pragma unroll
            for (int j = 0; j < 4; ++j)
                attL[(wr * 64 + i2 * 16 + kg * 4 + j) * 200 + wcg * 96 + n * 16 + lr] =
                    f2b(acc[i2][n][j]);
    __builtin_amdgcn_s_barrier();

    {
        const int wl = tid >> 3, j = tid & 7;
        const float scale = 0.03125f;             // C^-0.5 (d_model quirk)
        u16x8 qv[4], kv[4], vv[4];
#pragma unroll
        for (int t = 0; t < 4; ++t) {
            qv[t] = *(const u16x8*)&attL[(wl * 4 + t) * 200 + j * 8];
            kv[t] = *(const u16x8*)&attL[(wl * 4 + t) * 200 + 64 + j * 8];
            vv[t] = *(const u16x8*)&attL[(wl * 4 + t) * 200 + 128 + j * 8];
        }
        float qf[4][8], kf[4][8];
#pragma unroll
        for (int t = 0; t < 4; ++t)
#pragma unroll
            for (int c = 0; c < 8; ++c) { qf[t][c] = b2f(qv[t][c]); kf[t][c] = b2f(kv[t][c]); }
        float s[4][4];
#pragma unroll
        for (int t = 0; t < 4; ++t)
#pragma unroll
            for (int u2 = 0; u2 < 4; ++u2) {
                float p = qf[t][0] * kf[u2][0];
#pragma unroll
                for (int c = 1; c < 8; ++c) p += qf[t][c] * kf[u2][c];
                p += __shfl_xor(p, 1); p += __shfl_xor(p, 2); p += __shfl_xor(p, 4);
                s[t][u2] = p * scale;
            }
#pragma unroll
        for (int t = 0; t < 4; ++t) {
            const float m = fmaxf(fmaxf(s[t][0], s[t][1]), fmaxf(s[t][2], s[t][3]));
            const float e0 = expf(s[t][0] - m), e1 = expf(s[t][1] - m);
            const float e2 = expf(s[t][2] - m), e3 = expf(s[t][3] - m);
            const float inv = 1.f / (e0 + e1 + e2 + e3);
            u16x8 o;
#pragma unroll
            for (int c = 0; c < 8; ++c)
                o[c] = f2b((e0 * b2f(vv[0][c]) + e1 * b2f(vv[1][c]) +
                            e2 * b2f(vv[2][c]) + e3 * b2f(vv[3][c])) * inv);
            *(u16x8*)(Att + (size_t)(row0 + wl * 4 + t) * 1024 + nb * 64 + j * 8) = o;
        }
    }
#undef SB
}

// ---------- 256x256 8-wave GEMM (r8/r9 schedule) ----------
// MODE 3: +bias + bf16 resid -> f32 at natrow (FF2)
// MODE 6: +bias + bf16 resid -> bf16, + per-row stats atomics (proj)
// MODE 7: LN2-folded FF1: tt = rinv*v - rinv*mu*cvec[gc] + dvp[gc]; gelu -> bf16
template<int MODE>
__global__ __launch_bounds__(512, 2) void gemm256(
    const u16* __restrict__ A, const u16* __restrict__ Bt,
    const float* __restrict__ bias, const void* __restrict__ resid,
    void* __restrict__ Out, float* __restrict__ stats,
    const float* __restrict__ cvec, const float* __restrict__ dvp,
    int M, int N, int K, int LDA, int NB)
{
    extern __shared__ char lds[];
    const int NT = K >> 6;
    const int nblk = gridDim.x;
    const int x = blockIdx.x & 7, i = blockIdx.x >> 3;
    const int R = (nblk >> 3) / NB;
    const int ncs = NB >> 2;
    const int sc = i >> 4, u = i & 15;
    const int scr = sc / ncs, scc = sc - scr * ncs;
    const int mb = x * R + scr * 4 + (u >> 2);
    const int nb = scc * 4 + (u & 3);
    const int row0 = mb * 256, col0 = nb * 256;
    const int tid = threadIdx.x;
    const int w = tid >> 6, l = tid & 63;
    const int wr = w >> 2, wc = w & 3;
    const int lr = l & 15, kg = l >> 4;
    const int xs = (lr & 7) << 4;
    const int koff[2] = { (kg * 16) ^ xs, (64 + kg * 16) ^ xs };
    const int abase_l = wr * 8192 + lr * 128;
    const int bbase_l = wc * 4096 + lr * 128;

    f32x4 acc[2][2][4][2] = {};
    s16x8 a0[4][2], a1[4][2], b0[2][2], b1r[2][2];

    auto stage = [&](int ts, int item) {
        if (ts >= NT) return;
        const int d = ts & 1;
        const int isB = item & 1, h = item >> 1;
        char* lbase = lds + (isB ? 65536 : 0) + d * 32768 + h * 16384;
        const u16* gptr = isB ? Bt : A;
        const int ld = isB ? K : LDA;
        const int blk0 = (isB ? col0 : row0) + h * 128;
#pragma unroll
        for (int j = 0; j < 2; ++j) {
            const int p = j * 512 + tid;
            const int q = p ^ ((p >> 3) & 7);
            gll16(gptr + (size_t)(blk0 + (q >> 3)) * ld + ts * 64 + (q & 7) * 8,
                  lbase + (j * 8 + w) * 1024);
        }
    };

#define SB __builtin_amdgcn_sched_barrier(0)
#define LOAD_A(dst, qm) do { \
    _Pragma("unroll") for (int kk = 0; kk < 2; ++kk) \
    _Pragma("unroll") for (int i2 = 0; i2 < 4; ++i2) \
        dst[i2][kk] = *(const s16x8*)(Ab + (qm) * 16384 + abase_l + i2 * 2048 + koff[kk]); \
} while (0)
#define LOAD_B(dst, qn) do { \
    _Pragma("unroll") for (int kk = 0; kk < 2; ++kk) \
    _Pragma("unroll") for (int n = 0; n < 2; ++n) \
        dst[n][kk] = *(const s16x8*)(Bb + (qn) * 16384 + bbase_l + n * 2048 + koff[kk]); \
} while (0)
#define LGKM0 do { asm volatile("s_waitcnt lgkmcnt(0)" ::: "memory"); SB; } while (0)
#define MFMA_Q(qm, qn, aa, bb) do { \
    __builtin_amdgcn_s_setprio(1); \
    _Pragma("unroll") for (int kk = 0; kk < 2; ++kk) \
    _Pragma("unroll") for (int i2 = 0; i2 < 4; ++i2) \
    _Pragma("unroll") for (int n = 0; n < 2; ++n) \
        acc[qm][qn][i2][n] = __builtin_amdgcn_mfma_f32_16x16x32_bf16( \
            aa[i2][kk], bb[n][kk], acc[qm][qn][i2][n], 0, 0, 0); \
    __builtin_amdgcn_s_setprio(0); SB; \
} while (0)
#define GATE(NSTR) do { \
    asm volatile("s_waitcnt vmcnt(" NSTR ")" ::: "memory"); \
    __builtin_amdgcn_s_barrier(); SB; \
} while (0)

    stage(0, 0); stage(0, 1); stage(0, 2); stage(0, 3);

    for (int t = 0; t < NT - 1; ++t) {
        const char* Ab = lds + (t & 1) * 32768;
        const char* Bb = lds + 65536 + (t & 1) * 32768;
        GATE("4");
        LOAD_A(a0, 0); LOAD_B(b0, 0); SB;
        stage(t + 1, 0); SB;
        LGKM0;
        MFMA_Q(0, 0, a0, b0);
        GATE("4");
        LOAD_A(a1, 1); SB;
        stage(t + 1, 1); SB;
        LGKM0;
        MFMA_Q(1, 0, a1, b0);
        GATE("4");
        LOAD_B(b1r, 1); SB;
        stage(t + 1, 2); SB;
        LGKM0;
        MFMA_Q(1, 1, a1, b1r);
        stage(t + 1, 3); SB;
        MFMA_Q(0, 1, a0, b1r);
    }
    {
        const int t = NT - 1;
        const char* Ab = lds + (t & 1) * 32768;
        const char* Bb = lds + 65536 + (t & 1) * 32768;
        GATE("4");
        LOAD_A(a0, 0); LOAD_B(b0, 0); SB;
        LGKM0;
        MFMA_Q(0, 0, a0, b0);
        GATE("2");
        LOAD_A(a1, 1); SB;
        LGKM0;
        MFMA_Q(1, 0, a1, b0);
        GATE("0");
        LOAD_B(b1r, 1); SB;
        LGKM0;
        MFMA_Q(1, 1, a1, b1r);
        MFMA_Q(0, 1, a0, b1r);
    }
#undef SB
#undef LOAD_A
#undef LOAD_B
#undef LGKM0
#undef MFMA_Q
#undef GATE

    // ---- epilogues ----
    if (MODE == 3) {
#pragma unroll
        for (int qm = 0; qm < 2; ++qm)
#pragma unroll
        for (int i2 = 0; i2 < 4; ++i2) {
            const int grb = row0 + qm * 128 + wr * 64 + i2 * 16 + kg * 4;
#pragma unroll
            for (int qn = 0; qn < 2; ++qn)
#pragma unroll
            for (int n = 0; n < 2; ++n) {
                const int gc = col0 + qn * 128 + wc * 32 + n * 16 + lr;
#pragma unroll
                for (int j = 0; j < 4; ++j) {
                    const int gr = grb + j;
                    ((float*)Out)[(size_t)natrow(gr) * N + gc] =
                        acc[qm][qn][i2][n][j] + bias[gc] + b2f(((const u16*)resid)[(size_t)gr * N + gc]);
                }
            }
        }
    } else if (MODE == 6) {
        // proj: write bf16 xr + per-row sum/sumsq atomics (LN2 stats)
#pragma unroll
        for (int qm = 0; qm < 2; ++qm)
#pragma unroll
        for (int i2 = 0; i2 < 4; ++i2)
#pragma unroll
        for (int j = 0; j < 4; ++j) {
            const int gr = row0 + qm * 128 + wr * 64 + i2 * 16 + kg * 4 + j;
            float s1 = 0.f, s2 = 0.f;
#pragma unroll
            for (int qn = 0; qn < 2; ++qn)
#pragma unroll
            for (int n = 0; n < 2; ++n) {
                const int gc = col0 + qn * 128 + wc * 32 + n * 16 + lr;
                const float rs = acc[qm][qn][i2][n][j] + bias[gc] +
                                 b2f(((const u16*)resid)[(size_t)gr * N + gc]);
                ((u16*)Out)[(size_t)gr * N + gc] = f2b(rs);
                s1 += rs; s2 += rs * rs;
            }
#pragma unroll
            for (int o = 1; o < 16; o <<= 1) { s1 += __shfl_xor(s1, o); s2 += __shfl_xor(s2, o); }
            if (lr == 0) {
                atomicAdd(&stats[gr * 2],     s1);
                atomicAdd(&stats[gr * 2 + 1], s2);
            }
        }
    } else {
        // MODE 7: FF1 with algebraic LN2 fold + gelu
#pragma unroll
        for (int qm = 0; qm < 2; ++qm)
#pragma unroll
        for (int i2 = 0; i2 < 4; ++i2)
#pragma unroll
        for (int j = 0; j < 4; ++j) {
            const int gr = row0 + qm * 128 + wr * 64 + i2 * 16 + kg * 4 + j;
            const float sm  = stats[gr * 2], sq = stats[gr * 2 + 1];
            const float mu  = sm * (1.f / 1024.f);
            const float var = sq * (1.f / 1024.f) - mu * mu;
            const float ri  = rsqrtf(var + 1e-5f);
            const float rim = -ri * mu;
#pragma unroll
            for (int qn = 0; qn < 2; ++qn)
#pragma unroll
            for (int n = 0; n < 2; ++n) {
                const int gc = col0 + qn * 128 + wc * 32 + n * 16 + lr;
                const float tt = ri * acc[qm][qn][i2][n][j] + rim * cvec[gc] + dvp[gc];
                ((u16*)Out)[(size_t)gr * N + gc] =
                    f2b(0.5f * tt * (1.f + erff(tt * 0.70710678118f)));
            }
        }
    }
}

// ---------- launch ----------
extern "C" void kernel_launch(void* const* d_in, const int* in_sizes, int n_in,
                              void* d_out, int out_size, void* d_ws, size_t ws_size,
                              hipStream_t stream)
{
    const float* x    = (const float*)d_in[0];
    const float* ln1g = (const float*)d_in[1];
    const float* ln1b = (const float*)d_in[2];
    const float* Wq   = (const float*)d_in[3];
    const float* Wk   = (const float*)d_in[4];
    const float* Wv   = (const float*)d_in[5];
    const float* Wp   = (const float*)d_in[6];
    const float* bp   = (const float*)d_in[7];
    const float* ln2g = (const float*)d_in[8];
    const float* ln2b = (const float*)d_in[9];
    const float* W1   = (const float*)d_in[10];
    const float* b1   = (const float*)d_in[11];
    const float* W2   = (const float*)d_in[12];
    const float* b2   = (const float*)d_in[13];
    float* out = (float*)d_out;

    char* ws = (char*)d_ws;
    const size_t MB = 1024 * 1024;
    u16*   xr_b  = (u16*)ws;                      // 32MB: xr bf16 (residual spine)
    u16*   xw_b  = (u16*)(ws + 32 * MB);          // 32MB: ln1(x) windowed bf16
    u16*   att   = (u16*)(ws + 64 * MB);          // 32MB: fused attn output
    u16*   h1b   = (u16*)(ws + 96 * MB);          // 32MB
    float* stats = (float*)(ws + 128 * MB);       // 128KB: [16384][2] sum/sumsq
    float* cvec  = (float*)(ws + 128 * MB + 131072);   // 4KB
    float* dvp   = (float*)(ws + 128 * MB + 135168);   // 4KB
    u16*   WqkvT = (u16*)(ws + 192 * MB);         // 6MB [3072][1024] head-interleaved
    u16*   WpT   = (u16*)(ws + 198 * MB);         // 3 x 2MB (Wp, g*W1, W2)
    u16*   W1T   = WpT + (1u << 20);
    u16*   W2T   = W1T + (1u << 20);

    (void)hipFuncSetAttribute((const void*)gemm_qkv_attn, hipFuncAttributeMaxDynamicSharedMemorySize, 114688);
    (void)hipFuncSetAttribute((const void*)gemm256<3>, hipFuncAttributeMaxDynamicSharedMemorySize, 131072);
    (void)hipFuncSetAttribute((const void*)gemm256<6>, hipFuncAttributeMaxDynamicSharedMemorySize, 131072);
    (void)hipFuncSetAttribute((const void*)gemm256<7>, hipFuncAttributeMaxDynamicSharedMemorySize, 131072);

    const int M = 16384, K = 1024;

    // zero stats + cvec + dvp (graph-captured, runs every replay)
    (void)hipMemsetAsync(ws + 128 * MB, 0, 139264, stream);

    // merged prologue: weight transposes (+g-fold) + LN1 + cvec/dvec
    prologue_kernel<<<22592, 256, 0, stream>>>(x, ln1g, ln1b, Wq, Wk, Wv,
                                               Wp, W1, W2, ln2g, ln2b, b1,
                                               WqkvT, WpT, xw_b, cvec, dvp);

    // fused: att = windowed-attention(xw @ [Wq|Wk|Wv])
    gemm_qkv_attn<<<1024, 512, 114688, stream>>>(xw_b, WqkvT, att, M, K);

    // xr = att @ Wp + bp + xw -> bf16 + LN2 stats atomics
    gemm256<6><<<256, 512, 131072, stream>>>(att, WpT, bp, xw_b, xr_b,
                                             stats, nullptr, nullptr, M, 1024, K, K, 4);

    // h1 = gelu(ln2-fold: xr @ (g.W1) ...)
    gemm256<7><<<256, 512, 131072, stream>>>(xr_b, W1T, nullptr, nullptr, h1b,
                                             stats, cvec, dvp, M, 1024, K, K, 4);

    // out[natrow] = h1 @ W2 + b2 + xr
    gemm256<3><<<256, 512, 131072, stream>>>(h1b, W2T, b2, xr_b, out,
                                             nullptr, nullptr, nullptr, M, 1024, K, K, 4);
}

// Round 15
// 285.495 us; speedup vs baseline: 1.0665x; 1.0665x over previous
//
#include <hip/hip_runtime.h>
#include <math.h>

typedef unsigned short u16;
typedef unsigned int   u32;

using f32x4  = __attribute__((ext_vector_type(4))) float;
using s16x8  = __attribute__((ext_vector_type(8))) short;
using u16x8  = __attribute__((ext_vector_type(8))) unsigned short;

// ---------- helpers ----------
__device__ __forceinline__ u16 f2b(float f) {           // fp32 -> bf16 RNE
    u32 u = __float_as_uint(f);
    u += 0x7FFFu + ((u >> 16) & 1u);
    return (u16)(u >> 16);
}
__device__ __forceinline__ float b2f(u16 u) { return __uint_as_float(((u32)u) << 16); }

// window-order row R -> natural token row (b*256 + i*16 + j)
__device__ __forceinline__ int natrow(int R) {
    int b = R >> 8, r8 = R & 255, w = r8 >> 2, t = r8 & 3;
    return (b << 8) + ((((w >> 3) << 1) + (t >> 1)) << 4) + ((w & 7) << 1) + (t & 1);
}

__device__ __forceinline__ void gll16(const void* g, void* l) {
    __builtin_amdgcn_global_load_lds(
        (const __attribute__((address_space(1))) void*)g,
        (__attribute__((address_space(3))) void*)l, 16, 0, 0);
}

// ---------- merged prologue: weight transposes + LN1(window-gather) ----------
// bid [0,3072): transpose_qkv  (z=bid>>6: Wq h0-15 | Wk | Wv; head-interleaved out)
// bid [3072,6144): transpose_pw (Wp, W1, W2 -> contiguous)
// bid [6144,22528): ln1 row R = bid-6144, natrow gather, f32 in -> bf16 out
__global__ __launch_bounds__(256) void prologue_kernel(
    const float* __restrict__ x, const float* __restrict__ ln1g, const float* __restrict__ ln1b,
    const float* __restrict__ Wq, const float* __restrict__ Wk, const float* __restrict__ Wv,
    const float* __restrict__ Wp, const float* __restrict__ W1, const float* __restrict__ W2,
    u16* __restrict__ WqkvT, u16* __restrict__ WpT, u16* __restrict__ xw_b)
{
    const int bid = blockIdx.x;
    const int tid = threadIdx.x;
    if (bid < 6144) {
        // ---- transpose role: [R][C] f32 -> [C][R] bf16 ----
        __shared__ float tile[32][33];
        const float* in; u16* out; int Rr, Cc, bx, by;
        if (bid < 3072) {
            const int z = bid >> 6, r = bid & 63;
            bx = r & 1; by = r >> 1;
            in  = (z < 16 ? Wq : z < 32 ? Wk : Wv) + (size_t)(z & 15) * 65536;
            const int h = z & 15, sec = z < 16 ? 0 : (z < 32 ? 1 : 2);
            out = WqkvT + ((size_t)h * 192 + sec * 64) * 1024;
            Rr = 1024; Cc = 64;
        } else {
            const int t = bid - 3072, z = t >> 10, r = t & 1023;
            bx = r & 31; by = r >> 5;
            in  = z == 0 ? Wp : z == 1 ? W1 : W2;
            out = WpT + (size_t)z * 1048576;
            Rr = 1024; Cc = 1024;
        }
        const int tx = tid & 31, ty = tid >> 5;
        const int c  = bx * 32 + tx;
        const int r0 = by * 32;
#pragma unroll
        for (int i = 0; i < 32; i += 8) tile[ty + i][tx] = in[(size_t)(r0 + ty + i) * Cc + c];
        __syncthreads();
        const int orow0 = bx * 32;
        const int ocol  = r0 + tx;
#pragma unroll
        for (int i = 0; i < 32; i += 8)
            out[(size_t)(orow0 + ty + i) * Rr + ocol] = f2b(tile[tx][ty + i]);
    } else {
        // ---- LN1 role ----
        __shared__ float red[8];
        const int R   = bid - 6144;
        const int src = natrow(R);
        const float4 v = ((const float4*)(x + (size_t)src * 1024))[tid];
        float s  = v.x + v.y + v.z + v.w;
        float s2 = v.x * v.x + v.y * v.y + v.z * v.z + v.w * v.w;
#pragma unroll
        for (int o = 32; o; o >>= 1) { s += __shfl_xor(s, o); s2 += __shfl_xor(s2, o); }
        const int w = tid >> 6, l = tid & 63;
        if (l == 0) { red[w] = s; red[w + 4] = s2; }
        __syncthreads();
        s  = red[0] + red[1] + red[2] + red[3];
        s2 = red[4] + red[5] + red[6] + red[7];
        const float mean = s * (1.f / 1024.f);
        const float var  = s2 * (1.f / 1024.f) - mean * mean;
        const float rinv = rsqrtf(var + 1e-5f);
        const float4 gv = ((const float4*)ln1g)[tid];
        const float4 bv = ((const float4*)ln1b)[tid];
        ((ushort4*)(xw_b + (size_t)R * 1024))[tid] = make_ushort4(
            f2b((v.x - mean) * rinv * gv.x + bv.x), f2b((v.y - mean) * rinv * gv.y + bv.y),
            f2b((v.z - mean) * rinv * gv.z + bv.z), f2b((v.w - mean) * rinv * gv.w + bv.w));
    }
}

// ---------- LayerNorm (LN2): bf16 in, bf16 out, identity row map ----------
__global__ __launch_bounds__(256) void ln2_kernel(
    const u16* __restrict__ X, const float* __restrict__ g, const float* __restrict__ bta,
    u16* __restrict__ outB)
{
    const int R = blockIdx.x;
    const ushort4 r = ((const ushort4*)(X + (size_t)R * 1024))[threadIdx.x];
    const float x0 = b2f(r.x), x1 = b2f(r.y), x2 = b2f(r.z), x3 = b2f(r.w);
    float s  = x0 + x1 + x2 + x3;
    float s2 = x0 * x0 + x1 * x1 + x2 * x2 + x3 * x3;
#pragma unroll
    for (int o = 32; o; o >>= 1) { s += __shfl_xor(s, o); s2 += __shfl_xor(s2, o); }
    __shared__ float red[8];
    const int w = threadIdx.x >> 6, l = threadIdx.x & 63;
    if (l == 0) { red[w] = s; red[w + 4] = s2; }
    __syncthreads();
    s  = red[0] + red[1] + red[2] + red[3];
    s2 = red[4] + red[5] + red[6] + red[7];
    const float mean = s * (1.f / 1024.f);
    const float var  = s2 * (1.f / 1024.f) - mean * mean;
    const float rinv = rsqrtf(var + 1e-5f);
    const float4 gv = ((const float4*)g)[threadIdx.x];
    const float4 bv = ((const float4*)bta)[threadIdx.x];
    ((ushort4*)(outB + (size_t)R * 1024))[threadIdx.x] = make_ushort4(
        f2b((x0 - mean) * rinv * gv.x + bv.x), f2b((x1 - mean) * rinv * gv.y + bv.y),
        f2b((x2 - mean) * rinv * gv.z + bv.z), f2b((x3 - mean) * rinv * gv.w + bv.w));
}

// ---------- FUSED QKV GEMM + windowed attention ----------
__global__ __launch_bounds__(512, 2) void gemm_qkv_attn(
    const u16* __restrict__ A, const u16* __restrict__ Bt,
    u16* __restrict__ Att, int M, int K)
{
    extern __shared__ char lds[];
    const int NT = K >> 6;                        // 16
    const int x = blockIdx.x & 7, i = blockIdx.x >> 3;
    const int sc = i >> 4, u = i & 15;
    const int scr = sc >> 2, scc = sc & 3;
    const int mb = x * 8 + scr * 4 + (u >> 2);
    const int nb = scc * 4 + (u & 3);             // head index 0..15
    const int row0 = mb * 256, col0 = nb * 192;
    const int tid = threadIdx.x;
    const int w = tid >> 6, l = tid & 63;
    const int wr = w & 3, wcg = w >> 2;
    const int lr = l & 15, kg = l >> 4;
    const int xs = (lr & 7) << 4;
    const int koff[2] = { (kg * 16) ^ xs, (64 + kg * 16) ^ xs };
    const int abase_l = wr * 8192 + lr * 128;
    const int bbase_l = wcg * 12288 + lr * 128;

    f32x4 acc[4][6] = {};
    s16x8 a[4][2], b[6][2];

    auto stageQ = [&](int ts) {
        if (ts >= NT) return;
        const int d = ts & 1, gcolb = ts * 64;
        const int sl = (tid & 7) ^ ((tid >> 3) & 7);
#pragma unroll
        for (int h2 = 0; h2 < 2; ++h2)
#pragma unroll
            for (int j = 0; j < 2; ++j) {
                const int c = j * 512 + tid;
                const int s2 = (c & 7) ^ ((c >> 3) & 7);
                gll16(A + (size_t)(row0 + h2 * 128 + (c >> 3)) * K + gcolb + s2 * 8,
                      lds + d * 32768 + h2 * 16384 + (j * 8 + w) * 1024);
            }
#pragma unroll
        for (int k2 = 0; k2 < 3; ++k2)
            gll16(Bt + (size_t)(col0 + k2 * 64 + (tid >> 3)) * K + gcolb + sl * 8,
                  lds + 65536 + d * 24576 + k2 * 8192 + w * 1024);
    };

#define SB __builtin_amdgcn_sched_barrier(0)
#define WLq(NS) do { asm volatile("s_waitcnt lgkmcnt(" NS ")" ::: "memory"); SB; } while (0)

    stageQ(0);

    for (int t = 0; t < NT; ++t) {
        const char* Ab = lds + (t & 1) * 32768 + abase_l;
        const char* Bb = lds + 65536 + (t & 1) * 24576 + bbase_l;
        asm volatile("s_waitcnt vmcnt(0)" ::: "memory");
        __builtin_amdgcn_s_barrier(); SB;
#pragma unroll
        for (int i2 = 0; i2 < 4; ++i2) a[i2][0] = *(const s16x8*)(Ab + i2 * 2048 + koff[0]);
#pragma unroll
        for (int n = 0; n < 6; ++n)   b[n][0]  = *(const s16x8*)(Bb + n * 2048 + koff[0]);
        SB;
#pragma unroll
        for (int i2 = 0; i2 < 4; ++i2) a[i2][1] = *(const s16x8*)(Ab + i2 * 2048 + koff[1]);
#pragma unroll
        for (int n = 0; n < 6; ++n)   b[n][1]  = *(const s16x8*)(Bb + n * 2048 + koff[1]);
        SB;
        stageQ(t + 1); SB;
        __builtin_amdgcn_s_setprio(1);
        WLq("10");
#pragma unroll
        for (int i2 = 0; i2 < 4; ++i2)
#pragma unroll
            for (int n = 0; n < 6; ++n)
                acc[i2][n] = __builtin_amdgcn_mfma_f32_16x16x32_bf16(a[i2][0], b[n][0], acc[i2][n], 0, 0, 0);
        SB;
        WLq("0");
#pragma unroll
        for (int i2 = 0; i2 < 4; ++i2)
#pragma unroll
            for (int n = 0; n < 6; ++n)
                acc[i2][n] = __builtin_amdgcn_mfma_f32_16x16x32_bf16(a[i2][1], b[n][1], acc[i2][n], 0, 0, 0);
        __builtin_amdgcn_s_setprio(0); SB;
    }
#undef WLq

    // epilogue: acc -> LDS (bf16, pitch 200) -> windowed attention -> Att
    __builtin_amdgcn_s_barrier();
    u16* attL = (u16*)lds;
#pragma unroll
    for (int i2 = 0; i2 < 4; ++i2)
#pragma unroll
        for (int n = 0; n < 6; ++n)
#pragma unroll
            for (int j = 0; j < 4; ++j)
                attL[(wr * 64 + i2 * 16 + kg * 4 + j) * 200 + wcg * 96 + n * 16 + lr] =
                    f2b(acc[i2][n][j]);
    __builtin_amdgcn_s_barrier();

    {
        const int wl = tid >> 3, j = tid & 7;
        const float scale = 0.03125f;             // C^-0.5 (d_model quirk)
        u16x8 qv[4], kv[4], vv[4];
#pragma unroll
        for (int t = 0; t < 4; ++t) {
            qv[t] = *(const u16x8*)&attL[(wl * 4 + t) * 200 + j * 8];
            kv[t] = *(const u16x8*)&attL[(wl * 4 + t) * 200 + 64 + j * 8];
            vv[t] = *(const u16x8*)&attL[(wl * 4 + t) * 200 + 128 + j * 8];
        }
        float qf[4][8], kf[4][8];
#pragma unroll
        for (int t = 0; t < 4; ++t)
#pragma unroll
            for (int c = 0; c < 8; ++c) { qf[t][c] = b2f(qv[t][c]); kf[t][c] = b2f(kv[t][c]); }
        float s[4][4];
#pragma unroll
        for (int t = 0; t < 4; ++t)
#pragma unroll
            for (int u2 = 0; u2 < 4; ++u2) {
                float p = qf[t][0] * kf[u2][0];
#pragma unroll
                for (int c = 1; c < 8; ++c) p += qf[t][c] * kf[u2][c];
                p += __shfl_xor(p, 1); p += __shfl_xor(p, 2); p += __shfl_xor(p, 4);
                s[t][u2] = p * scale;
            }
#pragma unroll
        for (int t = 0; t < 4; ++t) {
            const float m = fmaxf(fmaxf(s[t][0], s[t][1]), fmaxf(s[t][2], s[t][3]));
            const float e0 = expf(s[t][0] - m), e1 = expf(s[t][1] - m);
            const float e2 = expf(s[t][2] - m), e3 = expf(s[t][3] - m);
            const float inv = 1.f / (e0 + e1 + e2 + e3);
            u16x8 o;
#pragma unroll
            for (int c = 0; c < 8; ++c)
                o[c] = f2b((e0 * b2f(vv[0][c]) + e1 * b2f(vv[1][c]) +
                            e2 * b2f(vv[2][c]) + e3 * b2f(vv[3][c])) * inv);
            *(u16x8*)(Att + (size_t)(row0 + wl * 4 + t) * 1024 + nb * 64 + j * 8) = o;
        }
    }
#undef SB
}

// ---------- 256x256 8-wave GEMM (r8/r9 schedule) ----------
// MODE 2: gelu(+bias) -> bf16   MODE 3: +bias + bf16 resid -> f32 at natrow
// MODE 5: +bias + bf16 resid -> bf16
template<int MODE>
__global__ __launch_bounds__(512, 2) void gemm256(
    const u16* __restrict__ A, const u16* __restrict__ Bt,
    const float* __restrict__ bias, const void* __restrict__ resid,
    void* __restrict__ Out, int M, int N, int K, int LDA, int NB)
{
    extern __shared__ char lds[];
    const int NT = K >> 6;
    const int nblk = gridDim.x;
    const int x = blockIdx.x & 7, i = blockIdx.x >> 3;
    const int R = (nblk >> 3) / NB;
    const int ncs = NB >> 2;
    const int sc = i >> 4, u = i & 15;
    const int scr = sc / ncs, scc = sc - scr * ncs;
    const int mb = x * R + scr * 4 + (u >> 2);
    const int nb = scc * 4 + (u & 3);
    const int row0 = mb * 256, col0 = nb * 256;
    const int tid = threadIdx.x;
    const int w = tid >> 6, l = tid & 63;
    const int wr = w >> 2, wc = w & 3;
    const int lr = l & 15, kg = l >> 4;
    const int xs = (lr & 7) << 4;
    const int koff[2] = { (kg * 16) ^ xs, (64 + kg * 16) ^ xs };
    const int abase_l = wr * 8192 + lr * 128;
    const int bbase_l = wc * 4096 + lr * 128;

    f32x4 acc[2][2][4][2] = {};
    s16x8 a0[4][2], a1[4][2], b0[2][2], b1[2][2];

    auto stage = [&](int ts, int item) {
        if (ts >= NT) return;
        const int d = ts & 1;
        const int isB = item & 1, h = item >> 1;
        char* lbase = lds + (isB ? 65536 : 0) + d * 32768 + h * 16384;
        const u16* gptr = isB ? Bt : A;
        const int ld = isB ? K : LDA;
        const int blk0 = (isB ? col0 : row0) + h * 128;
#pragma unroll
        for (int j = 0; j < 2; ++j) {
            const int p = j * 512 + tid;
            const int q = p ^ ((p >> 3) & 7);
            gll16(gptr + (size_t)(blk0 + (q >> 3)) * ld + ts * 64 + (q & 7) * 8,
                  lbase + (j * 8 + w) * 1024);
        }
    };

#define SB __builtin_amdgcn_sched_barrier(0)
#define LOAD_A(dst, qm) do { \
    _Pragma("unroll") for (int kk = 0; kk < 2; ++kk) \
    _Pragma("unroll") for (int i2 = 0; i2 < 4; ++i2) \
        dst[i2][kk] = *(const s16x8*)(Ab + (qm) * 16384 + abase_l + i2 * 2048 + koff[kk]); \
} while (0)
#define LOAD_B(dst, qn) do { \
    _Pragma("unroll") for (int kk = 0; kk < 2; ++kk) \
    _Pragma("unroll") for (int n = 0; n < 2; ++n) \
        dst[n][kk] = *(const s16x8*)(Bb + (qn) * 16384 + bbase_l + n * 2048 + koff[kk]); \
} while (0)
#define LGKM0 do { asm volatile("s_waitcnt lgkmcnt(0)" ::: "memory"); SB; } while (0)
#define MFMA_Q(qm, qn, aa, bb) do { \
    __builtin_amdgcn_s_setprio(1); \
    _Pragma("unroll") for (int kk = 0; kk < 2; ++kk) \
    _Pragma("unroll") for (int i2 = 0; i2 < 4; ++i2) \
    _Pragma("unroll") for (int n = 0; n < 2; ++n) \
        acc[qm][qn][i2][n] = __builtin_amdgcn_mfma_f32_16x16x32_bf16( \
            aa[i2][kk], bb[n][kk], acc[qm][qn][i2][n], 0, 0, 0); \
    __builtin_amdgcn_s_setprio(0); SB; \
} while (0)
#define GATE(NSTR) do { \
    asm volatile("s_waitcnt vmcnt(" NSTR ")" ::: "memory"); \
    __builtin_amdgcn_s_barrier(); SB; \
} while (0)

    stage(0, 0); stage(0, 1); stage(0, 2); stage(0, 3);

    for (int t = 0; t < NT - 1; ++t) {
        const char* Ab = lds + (t & 1) * 32768;
        const char* Bb = lds + 65536 + (t & 1) * 32768;
        GATE("4");
        LOAD_A(a0, 0); LOAD_B(b0, 0); SB;
        stage(t + 1, 0); SB;
        LGKM0;
        MFMA_Q(0, 0, a0, b0);
        GATE("4");
        LOAD_A(a1, 1); SB;
        stage(t + 1, 1); SB;
        LGKM0;
        MFMA_Q(1, 0, a1, b0);
        GATE("4");
        LOAD_B(b1, 1); SB;
        stage(t + 1, 2); SB;
        LGKM0;
        MFMA_Q(1, 1, a1, b1);
        stage(t + 1, 3); SB;
        MFMA_Q(0, 1, a0, b1);
    }
    {
        const int t = NT - 1;
        const char* Ab = lds + (t & 1) * 32768;
        const char* Bb = lds + 65536 + (t & 1) * 32768;
        GATE("4");
        LOAD_A(a0, 0); LOAD_B(b0, 0); SB;
        LGKM0;
        MFMA_Q(0, 0, a0, b0);
        GATE("2");
        LOAD_A(a1, 1); SB;
        LGKM0;
        MFMA_Q(1, 0, a1, b0);
        GATE("0");
        LOAD_B(b1, 1); SB;
        LGKM0;
        MFMA_Q(1, 1, a1, b1);
        MFMA_Q(0, 1, a0, b1);
    }
#undef SB
#undef LOAD_A
#undef LOAD_B
#undef LGKM0
#undef MFMA_Q
#undef GATE

#pragma unroll
    for (int qm = 0; qm < 2; ++qm)
#pragma unroll
    for (int i2 = 0; i2 < 4; ++i2) {
        const int grb = row0 + qm * 128 + wr * 64 + i2 * 16 + kg * 4;
#pragma unroll
        for (int qn = 0; qn < 2; ++qn)
#pragma unroll
        for (int n = 0; n < 2; ++n) {
            const int gc = col0 + qn * 128 + wc * 32 + n * 16 + lr;
#pragma unroll
            for (int j = 0; j < 4; ++j) {
                const int gr = grb + j;
                const float v = acc[qm][qn][i2][n][j];
                if (MODE == 2) {
                    const float tt = v + bias[gc];
                    ((u16*)Out)[(size_t)gr * N + gc] = f2b(0.5f * tt * (1.f + erff(tt * 0.70710678118f)));
                } else if (MODE == 3) {
                    ((float*)Out)[(size_t)natrow(gr) * N + gc] =
                        v + bias[gc] + b2f(((const u16*)resid)[(size_t)gr * N + gc]);
                } else {
                    ((u16*)Out)[(size_t)gr * N + gc] =
                        f2b(v + bias[gc] + b2f(((const u16*)resid)[(size_t)gr * N + gc]));
                }
            }
        }
    }
}

// ---------- launch ----------
extern "C" void kernel_launch(void* const* d_in, const int* in_sizes, int n_in,
                              void* d_out, int out_size, void* d_ws, size_t ws_size,
                              hipStream_t stream)
{
    const float* x    = (const float*)d_in[0];
    const float* ln1g = (const float*)d_in[1];
    const float* ln1b = (const float*)d_in[2];
    const float* Wq   = (const float*)d_in[3];
    const float* Wk   = (const float*)d_in[4];
    const float* Wv   = (const float*)d_in[5];
    const float* Wp   = (const float*)d_in[6];
    const float* bp   = (const float*)d_in[7];
    const float* ln2g = (const float*)d_in[8];
    const float* ln2b = (const float*)d_in[9];
    const float* W1   = (const float*)d_in[10];
    const float* b1   = (const float*)d_in[11];
    const float* W2   = (const float*)d_in[12];
    const float* b2   = (const float*)d_in[13];
    float* out = (float*)d_out;

    char* ws = (char*)d_ws;
    const size_t MB = 1024 * 1024;
    u16* xr_b  = (u16*)ws;                        // 32MB: xr bf16 (residual spine)
    u16* xw_b  = (u16*)(ws + 32 * MB);            // 32MB: ln1(x) windowed bf16
    u16* att   = (u16*)(ws + 64 * MB);            // 32MB: fused attn output
    u16* h1b   = (u16*)(ws + 96 * MB);            // 32MB
    u16* ln2bf = (u16*)(ws + 128 * MB);           // 32MB
    u16* WqkvT = (u16*)(ws + 192 * MB);           // 6MB [3072][1024] head-interleaved
    u16* WpT   = (u16*)(ws + 198 * MB);           // 3 x 2MB contiguous
    u16* W1T   = WpT + (1u << 20);
    u16* W2T   = W1T + (1u << 20);

    (void)hipFuncSetAttribute((const void*)gemm_qkv_attn, hipFuncAttributeMaxDynamicSharedMemorySize, 114688);
    (void)hipFuncSetAttribute((const void*)gemm256<2>, hipFuncAttributeMaxDynamicSharedMemorySize, 131072);
    (void)hipFuncSetAttribute((const void*)gemm256<3>, hipFuncAttributeMaxDynamicSharedMemorySize, 131072);
    (void)hipFuncSetAttribute((const void*)gemm256<5>, hipFuncAttributeMaxDynamicSharedMemorySize, 131072);

    const int M = 16384, K = 1024;

    // merged prologue: weight transposes + LN1 (one launch, 22528 blocks)
    prologue_kernel<<<22528, 256, 0, stream>>>(x, ln1g, ln1b, Wq, Wk, Wv,
                                               Wp, W1, W2, WqkvT, WpT, xw_b);

    // fused: att = windowed-attention(xw @ [Wq|Wk|Wv])
    gemm_qkv_attn<<<1024, 512, 114688, stream>>>(xw_b, WqkvT, att, M, K);

    // xr = att @ Wp + bp + xw  -> bf16 spine
    gemm256<5><<<256, 512, 131072, stream>>>(att, WpT, bp, xw_b, xr_b, M, 1024, K, K, 4);

    ln2_kernel<<<16384, 256, 0, stream>>>(xr_b, ln2g, ln2b, ln2bf);

    // h1 = gelu(ln2 @ W1 + b1)
    gemm256<2><<<256, 512, 131072, stream>>>(ln2bf, W1T, b1, nullptr, h1b, M, 1024, K, K, 4);

    // out[natrow] = h1 @ W2 + b2 + xr
    gemm256<3><<<256, 512, 131072, stream>>>(h1b, W2T, b2, xr_b, out, M, 1024, K, K, 4);
}